// Round 1
// baseline (575.128 us; speedup 1.0000x reference)
//
#include <hip/hip_runtime.h>

// BlockEnd: out[b,a,f] = (a < M[b]) ? relu( sum_r resid[b,a,r]*w[r,f] + node[b,a,f] ) : 0
// B=4096, A=RF=F=128. fp32 in/out; compute via bf16 MFMA (tolerance 1.59e-1 allows it).
//
// Strategy: memory-bound (~560 MB min traffic -> ~93 us floor at 6.3 TB/s).
//  - pre-kernel: w (128x128 f32) -> wT (f-major, bf16) in d_ws; L2-resident.
//  - main: 1 block per molecule, 4 waves; wave tile = 32 a-rows x 128 f.
//    MFMA 16x16x32 bf16 with A-operand = wT (m->f), B-operand = resid (n->a):
//    both fragments are 8 contiguous elements (k = quad*8+j), and the C layout
//    (row=quad*4+reg, col=lane&15) then gives each lane 4 consecutive f ->
//    float4 epilogue loads/stores. Zero LDS.
//  - waves fully above M: skip compute+reads, write float4 zeros.

typedef __bf16 bf16x8 __attribute__((ext_vector_type(8)));
typedef float f32x4 __attribute__((ext_vector_type(4)));

static_assert(sizeof(bf16x8) == 16, "bf16x8 must be 16B");
static_assert(sizeof(f32x4) == 16, "f32x4 must be 16B");

// wT[f*128 + r] = (bf16) w[r*128 + f].  16384 threads, coalesced writes,
// strided reads (w is 64 KB -> L2 after first touch; kernel is tiny).
__global__ __launch_bounds__(256) void wT_kernel(const float* __restrict__ w,
                                                 __bf16* __restrict__ wT) {
    int i = blockIdx.x * 256 + threadIdx.x;   // 0..16383
    int f = i >> 7;
    int r = i & 127;
    wT[i] = (__bf16)w[r * 128 + f];
}

__global__ __launch_bounds__(256) void blockend_kernel(
    const float* __restrict__ node,    // [B,128,128]
    const float* __restrict__ resid,   // [B,128,128]
    const __bf16* __restrict__ wT,     // [128(f),128(r)] bf16
    const int*   __restrict__ mol,     // [B,2] int32, M = mol[2b]
    float*       __restrict__ out)     // [B,128,128]
{
    const int b    = blockIdx.x;
    const int t    = threadIdx.x;
    const int wave = t >> 6;
    const int lane = t & 63;
    const int quad = lane >> 4;
    const int m16  = lane & 15;

    const int M      = mol[2 * b];
    const int a_base = wave * 32;

    const size_t base = (size_t)b * (128 * 128);
    float* outW = out + base + (size_t)a_base * 128;

    if (M <= a_base) {
        // whole wave masked: 32 rows x 128 cols of zeros, coalesced float4
        f32x4 z = {0.f, 0.f, 0.f, 0.f};
        f32x4* p = (f32x4*)outW;
#pragma unroll
        for (int it = 0; it < 16; ++it)
            p[it * 64 + lane] = z;
        return;
    }

    const float* residW = resid + base + (size_t)a_base * 128;
    const float* nodeW  = node  + base + (size_t)a_base * 128;

    f32x4 acc[2][8];
#pragma unroll
    for (int nt = 0; nt < 2; ++nt)
#pragma unroll
        for (int ft = 0; ft < 8; ++ft)
            acc[nt][ft] = (f32x4){0.f, 0.f, 0.f, 0.f};

#pragma unroll
    for (int kk = 0; kk < 4; ++kk) {
        const int k0 = kk * 32 + quad * 8;   // this lane's 8-contiguous K slice

        // B-operand fragments: resid[a = a_base + nt*16 + m16][k0..k0+7], f32 -> bf16
        bf16x8 rfrag[2];
#pragma unroll
        for (int nt = 0; nt < 2; ++nt) {
            const float* ap = residW + (nt * 16 + m16) * 128 + k0;
            f32x4 lo = *(const f32x4*)ap;
            f32x4 hi = *(const f32x4*)(ap + 4);
            bf16x8 v;
            v[0] = (__bf16)lo[0]; v[1] = (__bf16)lo[1];
            v[2] = (__bf16)lo[2]; v[3] = (__bf16)lo[3];
            v[4] = (__bf16)hi[0]; v[5] = (__bf16)hi[1];
            v[6] = (__bf16)hi[2]; v[7] = (__bf16)hi[3];
            rfrag[nt] = v;
        }

        // A-operand fragments: wT[f = ft*16 + m16][k0..k0+7] (bf16, 16B load, L2-hit)
#pragma unroll
        for (int ft = 0; ft < 8; ++ft) {
            bf16x8 wfrag = *(const bf16x8*)(wT + (ft * 16 + m16) * 128 + k0);
#pragma unroll
            for (int nt = 0; nt < 2; ++nt)
                acc[nt][ft] = __builtin_amdgcn_mfma_f32_16x16x32_bf16(
                    wfrag, rfrag[nt], acc[nt][ft], 0, 0, 0);
        }
    }

    // Epilogue. D[m=f][n=a]: row = quad*4 + reg (consecutive f), col = m16 (a).
    // Mask depends only on this lane's a -> uniform across all ft and reg.
#pragma unroll
    for (int nt = 0; nt < 2; ++nt) {
        const int a_local = nt * 16 + m16;
        const bool active = (a_base + a_local) < M;
#pragma unroll
        for (int ft = 0; ft < 8; ++ft) {
            const int off = a_local * 128 + ft * 16 + quad * 4;
            f32x4 v = {0.f, 0.f, 0.f, 0.f};
            if (active) {
                f32x4 nd = *(const f32x4*)(nodeW + off);
#pragma unroll
                for (int i = 0; i < 4; ++i) {
                    float x = acc[nt][ft][i] + nd[i];
                    v[i] = x > 0.f ? x : 0.f;
                }
            }
            *(f32x4*)(outW + off) = v;
        }
    }
}

extern "C" void kernel_launch(void* const* d_in, const int* in_sizes, int n_in,
                              void* d_out, int out_size, void* d_ws, size_t ws_size,
                              hipStream_t stream) {
    const float* node  = (const float*)d_in[0];   // node_features    [4096,128,128]
    const float* resid = (const float*)d_in[1];   // residual_features[4096,128,128]
    const float* w     = (const float*)d_in[2];   // w [128,128]
    const int*   mol   = (const int*)d_in[3];     // mol_slice [4096,2] int32
    float*       out   = (float*)d_out;
    __bf16*      wT    = (__bf16*)d_ws;           // 32 KB scratch

    wT_kernel<<<64, 256, 0, stream>>>(w, wT);
    blockend_kernel<<<4096, 256, 0, stream>>>(node, resid, wT, mol, out);
}